// Round 4
// baseline (71.940 us; speedup 1.0000x reference)
//
#include <hip/hip_runtime.h>

// DiffVolumeV2: out[b][c][d][h][x] = left[b][c][h][x] - right[b][c][h][clip(4x-d+1, 0, Wr-1)]
// B=4, C=32, H=80, Wl=160, Wr=640, D=48.
// Store-BW-bound: 314.6 MB out + 32.8 MB in => ~52us floor @ 6.9 TB/s (fill-kernel rate).
//
// R1/R3 (block=(bc,h), 640B runs): 72.5/69.5us = 5.0 TB/s. R2 (1280-block lockstep): 117us.
// R4: block=(bc, 4 h-rows), TPB=320, thread=(d-parity, m) with m fixed per thread:
//  - staging amortized 4x (13KB staged -> 123KB stored per block)
//  - per-d contiguous runs 2.56KB (~1.2 segments per wave-store vs ~1.6)
//  - d-loop body fully hoisted: 4 LDS reads + 1 float4 store + e-=2, op+=2 planes
//  - grid 2560 = 10 blocks/CU (6 resident, 4 queued) -- no R2-style lockstep

constexpr int Bc  = 4;
constexpr int Cc  = 32;
constexpr int Hc  = 80;
constexpr int WLc = 160;
constexpr int WRc = 640;
constexpr int RPAD = WRc + WRc / 32;     // 660: addr = c + (c>>5) kills stride-16 conflicts

constexpr int HB   = 4;                  // h rows per block
constexpr int NHB  = Hc / HB;            // 20
constexpr int TPB4 = 320;                // 2 d-parities x 160 (hl,g) slots

__global__ __launch_bounds__(TPB4) void diffvol48(
    const float* __restrict__ left, const float* __restrict__ right,
    float* __restrict__ out)
{
    constexpr int D = 48;
    __shared__ __align__(16) float lrow[HB * WLc];   // 640 floats, linear
    __shared__ float rrow[HB * RPAD];                // 2640 floats, padded rows

    const int blk = blockIdx.x;          // bc*NHB + hb
    const int hb  = blk % NHB;
    const int bc  = blk / NHB;
    const int h0  = hb * HB;

    const float* lp = left  + ((size_t)bc * Hc + h0) * WLc;
    const float* rp = right + ((size_t)bc * Hc + h0) * WRc;
    const int tid = threadIdx.x;

    // Stage left: 640 floats = 160 float4.
    if (tid < HB * WLc / 4)
        *(float4*)(lrow + tid * 4) = *(const float4*)(lp + tid * 4);
    // Stage right: 2560 floats = 640 float4 = exactly 2 per thread.
    #pragma unroll
    for (int it = 0; it < 2; ++it) {
        int i   = tid + it * TPB4;               // float4 index in [0,640)
        int row = i / (WRc / 4);                 // /160
        int c4  = (i - row * (WRc / 4)) * 4;
        float4 v = *(const float4*)(rp + row * WRc + c4);
        float* dst = rrow + row * RPAD;
        const float* vv = (const float*)&v;
        #pragma unroll
        for (int k = 0; k < 4; ++k) { int c = c4 + k; dst[c + (c >> 5)] = vv[k]; }
    }
    __syncthreads();

    // Thread coords: tid = dp*160 + m, m = hl*40 + g. All hoisted; only d walks.
    const int dp = tid / 160;                    // d parity: 0 or 1
    const int m  = tid - dp * 160;               // 0..159
    const int hl = m / 40;
    const int g  = m - hl * 40;

    const float4 lv  = *(const float4*)(lrow + m * 4);
    const float* lvp = (const float*)&lv;
    const float* rb  = rrow + hl * RPAD;
    int e = 16 * g + 1 - dp;                     // c_j = e + 4j; e -= 2 per iter
    float* op = out + (size_t)bc * (D * Hc * WLc) + (size_t)dp * (Hc * WLc)
                    + h0 * WLc + m * 4;

    #pragma unroll 6
    for (int k = 0; k < D / 2; ++k) {            // d = dp + 2k
        float4 v; float* vp = (float*)&v;
        #pragma unroll
        for (int j = 0; j < 4; ++j) {
            int c = e + 4 * j;                   // max 637 < 639: upper clip unreachable
            c = c < 0 ? 0 : c;
            vp[j] = lvp[j] - rb[c + (c >> 5)];
        }
        *(float4*)op = v;
        e -= 2;
        op += 2 * (Hc * WLc);
    }
}

// Generic fallback (any D): round-1/3 proven kernel.
constexpr int TPBG = 256;
__global__ __launch_bounds__(TPBG) void diffvol_generic(
    const float* __restrict__ left, const float* __restrict__ right,
    float* __restrict__ out, int D)
{
    __shared__ __align__(16) float lrow[WLc];
    __shared__ float rrow[RPAD];

    const int blk = blockIdx.x;
    const int h   = blk % Hc;
    const int bc  = blk / Hc;
    const float* lp = left  + ((size_t)bc * Hc + h) * WLc;
    const float* rp = right + ((size_t)bc * Hc + h) * WRc;
    const int tid = threadIdx.x;

    if (tid < WLc) lrow[tid] = lp[tid];
    for (int i = tid; i < WRc; i += TPBG) rrow[i + (i >> 5)] = rp[i];
    __syncthreads();

    float* ob = out + ((size_t)bc * D * Hc + h) * WLc;
    const int total = D * (WLc / 4);
    for (int t = tid; t < total; t += TPBG) {
        const int d  = t / (WLc / 4);
        const int g  = t - d * (WLc / 4);
        const int x0 = g * 4;
        const float4 lv = *(const float4*)(lrow + x0);
        float4 v;
        float* vp = (float*)&v;
        const float* lvp = (const float*)&lv;
        #pragma unroll
        for (int j = 0; j < 4; ++j) {
            int r = 4 * (x0 + j) - d + 1;
            r = r < 0 ? 0 : r;
            vp[j] = lvp[j] - rrow[r + (r >> 5)];
        }
        *(float4*)(ob + (size_t)d * (Hc * WLc) + x0) = v;
    }
}

extern "C" void kernel_launch(void* const* d_in, const int* in_sizes, int n_in,
                              void* d_out, int out_size, void* d_ws, size_t ws_size,
                              hipStream_t stream) {
    const float* left  = (const float*)d_in[0];
    const float* right = (const float*)d_in[1];
    float* out = (float*)d_out;

    const int D = out_size / (Bc * Cc * Hc * WLc);

    if (D == 48) {
        dim3 grid(Bc * Cc * NHB);    // 2560 blocks
        diffvol48<<<grid, TPB4, 0, stream>>>(left, right, out);
    } else {
        dim3 grid(Bc * Cc * Hc);     // 10240 blocks
        diffvol_generic<<<grid, TPBG, 0, stream>>>(left, right, out, D);
    }
}

// Round 6
// 66.364 us; speedup vs baseline: 1.0840x; 1.0840x over previous
//
#include <hip/hip_runtime.h>

// DiffVolumeV2: out[b][c][d][h][x] = left[b][c][h][x] - right[b][c][h][clip(4x-d+1, 0, Wr-1)]
// B=4, C=32, H=80, Wl=160, Wr=640, D=48.
// Store-BW-bound: 314.6 MB out + 32.8 MB in => ~50-55us floor at fill-kernel rates.
//
// History: R1 72.5us | R2 (1280-block lockstep) 117us | R3 69.5us | R4 (4-row blocks) 71.9us.
// R5: nontemporal experiment failed to COMPILE (builtin rejects HIP_vector_type).
// R6 = R5 with native clang ext_vector_type for the nontemporal builtins. Single
// variable vs R3: nt loads + nt stores (write-once stream => L2 allocation is
// pure overhead on both streams).

typedef float fx4 __attribute__((ext_vector_type(4)));   // native vector: OK for nontemporal builtins

constexpr int Bc  = 4;
constexpr int Cc  = 32;
constexpr int Hc  = 80;
constexpr int WLc = 160;
constexpr int WRc = 640;
constexpr int TPB = 256;
constexpr int GROUPS = WLc / 4;          // 40 float4 groups per row
constexpr int RPAD = WRc + WRc / 32;     // 660: addr = i + (i>>5) kills stride-16 conflicts

__global__ __launch_bounds__(TPB) void diffvol48(
    const float* __restrict__ left, const float* __restrict__ right,
    float* __restrict__ out)
{
    constexpr int D = 48;
    __shared__ __align__(16) float lrow[WLc];
    __shared__ float rrow[RPAD];

    const int blk = blockIdx.x;          // bc*80 + h
    const int h   = blk % Hc;
    const int bc  = blk / Hc;
    const float* lp = left  + ((size_t)bc * Hc + h) * WLc;
    const float* rp = right + ((size_t)bc * Hc + h) * WRc;
    const int tid = threadIdx.x;

    if (tid < GROUPS) {
        fx4 v = __builtin_nontemporal_load((const fx4*)(lp + tid * 4));
        *(fx4*)(lrow + tid * 4) = v;
    }
    if (tid < WRc / 4) {
        fx4 v = __builtin_nontemporal_load((const fx4*)(rp + tid * 4));
        #pragma unroll
        for (int k = 0; k < 4; ++k) { int c = tid * 4 + k; rrow[c + (c >> 5)] = v[k]; }
    }
    __syncthreads();

    int d = tid / GROUPS;                // 0..6 (one div, outside loop)
    int g = tid - d * GROUPS;            // 0..39
    int e = 16 * g - d;                  // gather base; c_j = e + 1 + 4j
    // out element offset: ((bc*D + d)*Hc + h)*WLc + g*4
    float* op = out + (size_t)bc * (D * Hc * WLc) + h * WLc
                    + (size_t)d * (Hc * WLc) + g * 4;

    // t += 256  <=>  g += 16 mod 40; no-wrap: d+=6, wrap: d+=7.
    #define SLOT_BODY                                                     \
    {                                                                     \
        const fx4 lv = *(const fx4*)(lrow + g * 4);                       \
        fx4 v;                                                            \
        _Pragma("unroll")                                                 \
        for (int j = 0; j < 4; ++j) {                                     \
            int c = e + 1 + 4 * j;                                        \
            c = c < 0 ? 0 : c;                                            \
            v[j] = lv[j] - rrow[c + (c >> 5)];                            \
        }                                                                 \
        __builtin_nontemporal_store(v, (fx4*)op);                         \
    }
    #define SLOT_ADVANCE                                                  \
    {                                                                     \
        int gn = g + 16;                                                  \
        bool wrap = gn >= GROUPS;                                         \
        g = wrap ? gn - GROUPS : gn;                                      \
        e += wrap ? -391 : 250;                                           \
        op += wrap ? (7 * Hc * WLc - 96) : (6 * Hc * WLc + 64);           \
    }

    #pragma unroll
    for (int it = 0; it < 7; ++it) { SLOT_BODY; SLOT_ADVANCE; }
    if (tid < (D * GROUPS - 7 * TPB)) {  // tid < 128: waves 0,1 — uniform per wave
        SLOT_BODY;
    }
    #undef SLOT_BODY
    #undef SLOT_ADVANCE
}

// Generic fallback (any D).
__global__ __launch_bounds__(TPB) void diffvol_generic(
    const float* __restrict__ left, const float* __restrict__ right,
    float* __restrict__ out, int D)
{
    __shared__ __align__(16) float lrow[WLc];
    __shared__ float rrow[RPAD];

    const int blk = blockIdx.x;
    const int h   = blk % Hc;
    const int bc  = blk / Hc;
    const float* lp = left  + ((size_t)bc * Hc + h) * WLc;
    const float* rp = right + ((size_t)bc * Hc + h) * WRc;
    const int tid = threadIdx.x;

    if (tid < WLc) lrow[tid] = lp[tid];
    for (int i = tid; i < WRc; i += TPB) rrow[i + (i >> 5)] = rp[i];
    __syncthreads();

    float* ob = out + ((size_t)bc * D * Hc + h) * WLc;
    const int total = D * (WLc / 4);
    for (int t = tid; t < total; t += TPB) {
        const int d  = t / (WLc / 4);
        const int g  = t - d * (WLc / 4);
        const int x0 = g * 4;
        const fx4 lv = *(const fx4*)(lrow + x0);
        fx4 v;
        #pragma unroll
        for (int j = 0; j < 4; ++j) {
            int r = 4 * (x0 + j) - d + 1;
            r = r < 0 ? 0 : r;
            v[j] = lv[j] - rrow[r + (r >> 5)];
        }
        __builtin_nontemporal_store(v, (fx4*)(ob + (size_t)d * (Hc * WLc) + x0));
    }
}

extern "C" void kernel_launch(void* const* d_in, const int* in_sizes, int n_in,
                              void* d_out, int out_size, void* d_ws, size_t ws_size,
                              hipStream_t stream) {
    const float* left  = (const float*)d_in[0];
    const float* right = (const float*)d_in[1];
    float* out = (float*)d_out;

    const int D = out_size / (Bc * Cc * Hc * WLc);

    dim3 grid(Bc * Cc * Hc);   // 10240 blocks, one per (b,c,h) row
    if (D == 48) {
        diffvol48<<<grid, TPB, 0, stream>>>(left, right, out);
    } else {
        diffvol_generic<<<grid, TPB, 0, stream>>>(left, right, out, D);
    }
}